// Round 9
// baseline (1240.256 us; speedup 1.0000x reference)
//
#include <hip/hip_runtime.h>
#include <hip/hip_bf16.h>

// Bahdanau additive attention, B=64, S=2048, H=1024 (fp32 in/out).
//   score[b,s] = sum_o v[o] * tanh( (enc[b,s,:].W_h[o,:]) + dp[b,o] )
//   weights = softmax_s(score);  context[b,:] = sum_s weights[b,s]*enc[b,s,:]
//
// R7 re-resubmit (two acquisition timeouts; never ran). (a) score GEMM back
// to the 128x128 m97-structure (R3 measured ~290us vs 256x256 8-phase
// 366-385us at K=1024 -- 16 K-tiles never amortize the deep pipeline);
// (b) cvt_enc pass DELETED (~122us BW): A staged as fp32 via global_load_lds
// (32KB tile, 16-chunk XOR swizzle), converted fp32->bf16 in-register
// (v_cvt_pk_bf16_f32, RTNE) right before MFMA. LDS 48KB -> 3 blocks/CU.
//
// d_ws: [0,256KB) dec_proj fp32 [64][1024]; [256KB,2.25MB) W_h bf16.

#define B_ 64
#define S_ 2048
#define H_ 1024

typedef __attribute__((ext_vector_type(8))) short short8;   // 8 bf16
typedef __attribute__((ext_vector_type(4))) float floatx4;  // MFMA acc

__device__ __forceinline__ short f2bf(float f) {
    unsigned u = __float_as_uint(f);
    return (short)((u + 0x7FFFu + ((u >> 16) & 1u)) >> 16);  // RTNE
}
__device__ __forceinline__ unsigned cvtpk(float a, float b) {  // low=bf16(a), high=bf16(b), RTNE
    unsigned r;
    asm("v_cvt_pk_bf16_f32 %0, %1, %2" : "=v"(r) : "v"(a), "v"(b));
    return r;
}
__device__ __forceinline__ void gload_lds16(const void* g, void* l) {
    __builtin_amdgcn_global_load_lds(
        (const __attribute__((address_space(1))) unsigned*)g,
        (__attribute__((address_space(3))) unsigned*)l, 16, 0, 0);
}

// ---------------- zero the score region (atomicAdd target) ----------------
__global__ __launch_bounds__(256) void zero_score_kernel(float* __restrict__ sc) {
    ((float4*)sc)[blockIdx.x * 256 + threadIdx.x] = make_float4(0.f, 0.f, 0.f, 0.f);
}

// ---------------- dec_proj[b,o] = sum_h dec[b,h] * W_s[o,h] ----------------
__global__ __launch_bounds__(256) void dec_proj_kernel(
        const float* __restrict__ dec, const float* __restrict__ Ws,
        float* __restrict__ dp) {
    __shared__ float sdec[H_];
    const int b = blockIdx.y;
    const int o = blockIdx.x * 256 + threadIdx.x;
    ((float4*)sdec)[threadIdx.x] = ((const float4*)(dec + b * H_))[threadIdx.x];
    __syncthreads();
    const float4* wr = (const float4*)(Ws + (size_t)o * H_);
    float acc = 0.f;
#pragma unroll 4
    for (int i = 0; i < H_ / 4; ++i) {
        float4 wv = wr[i];
        acc += sdec[4*i+0]*wv.x + sdec[4*i+1]*wv.y + sdec[4*i+2]*wv.z + sdec[4*i+3]*wv.w;
    }
    dp[b * H_ + o] = acc;
}

// ---------------- W_h fp32 -> bf16 ----------------
__global__ __launch_bounds__(256) void cvt_wh_kernel(
        const float* __restrict__ Wh, short* __restrict__ Wbf) {
    const int i = blockIdx.x * 256 + threadIdx.x;
    float4 f = ((const float4*)Wh)[i];
    *(short4*)&Wbf[i * 4] = make_short4(f2bf(f.x), f2bf(f.y), f2bf(f.z), f2bf(f.w));
}

// ================= fused score GEMM: 128x128, fp32-A direct =================
// grid.x = (M/128)*(N/128) = 1024*8; mtile = bid>>3, nb = bid&7 (nb-siblings
// dispatch-adjacent -> concurrent A-panel reads L2/L3-hit; R3-proven).
// A: fp32 [128][64] in LDS (32KB), 16-chunk XOR swizzle: LDS[row][c] holds
//    global 16B-chunk c^(row&15); conversion to bf16 happens at read time.
// B: bf16 [128][64] in LDS (16KB), 8-chunk XOR swizzle (R3-proven).
__global__ __launch_bounds__(256, 3) void score128_kernel(
        const float* __restrict__ enc, const short* __restrict__ Wbf,
        const float* __restrict__ dp, const float* __restrict__ v,
        float* __restrict__ score) {
    __shared__ float Asf[128 * 64];   // 32 KB
    __shared__ short Bs[128 * 64];    // 16 KB

    const int tid  = threadIdx.x;
    const int wave = tid >> 6;
    const int lane = tid & 63;
    const int l15  = lane & 15;
    const int quad = lane >> 4;
    const int wy   = wave & 1;        // m-half
    const int wx   = wave >> 1;       // n-half

    const int mtile = blockIdx.x >> 3;
    const int nb    = blockIdx.x & 7;
    const int m0    = mtile * 128;    // global row (b*S + s)
    const int n0    = nb * 128;
    const int b     = m0 >> 11;       // 16 M-tiles per batch

    floatx4 acc[4][4];
#pragma unroll
    for (int i = 0; i < 4; ++i)
#pragma unroll
        for (int j = 0; j < 4; ++j) acc[i][j] = (floatx4){0.f, 0.f, 0.f, 0.f};

    const int swz = l15 & 7;

    // staging bases (round-invariant swizzled global addresses)
    // B: thread t, round r -> row n = r*32 + (t>>3), chunk (t&7)^(n&7); n&7=(t>>3)&7
    const int bn  = tid >> 3;
    const short* gB0 = Wbf + (size_t)(n0 + bn) * H_ + ((tid & 7) ^ (bn & 7)) * 8;
    // A: thread t, round r -> row = r*16 + (t>>4), chunk (t&15)^(row&15); row&15=t>>4
    const int an  = tid >> 4;
    const float* gA0 = enc + (size_t)(m0 + an) * H_ + (((tid & 15) ^ an) << 2);

    // read bases
    const float4* aRow = (const float4*)Asf + (wy * 64 + l15) * 16;  // +i*256 +chunk
    const short*  bLds = Bs + (wx * 64 + l15) * 64;                  // +j*1024 +chunk*8

    for (int k0 = 0; k0 < H_; k0 += 64) {
        // ---- B tile: 4 rounds async 16B ----
#pragma unroll
        for (int r = 0; r < 4; ++r)
            gload_lds16(gB0 + (size_t)r * 32 * H_ + k0,
                        (void*)(Bs + (r * 256 + wave * 64) * 8));
        // ---- A tile fp32: 8 rounds async 16B ----
#pragma unroll
        for (int r = 0; r < 8; ++r)
            gload_lds16(gA0 + (size_t)r * 16 * H_ + k0,
                        (void*)(Asf + (r * 256 + wave * 64) * 4));
        __syncthreads();   // drains vmcnt

        // ---- compute: 2 kt x (4 a-frag cvt + 4 b-frag reads, 16 MFMA) ----
#pragma unroll
        for (int kt = 0; kt < 2; ++kt) {
            const int c0 = 8 * kt + 2 * quad;   // global 16B chunk (4 floats)
            short8 a2[4], b2[4];
#pragma unroll
            for (int i = 0; i < 4; ++i) {
                float4 f0 = aRow[i * 256 + (c0 ^ l15)];
                float4 f1 = aRow[i * 256 + ((c0 + 1) ^ l15)];
                union { short8 s; unsigned u[4]; } cv;
                cv.u[0] = cvtpk(f0.x, f0.y);
                cv.u[1] = cvtpk(f0.z, f0.w);
                cv.u[2] = cvtpk(f1.x, f1.y);
                cv.u[3] = cvtpk(f1.z, f1.w);
                a2[i] = cv.s;
            }
#pragma unroll
            for (int j = 0; j < 4; ++j)
                b2[j] = *(const short8*)(bLds + j * 1024 + (((kt * 4 + quad) ^ swz) * 8));
#pragma unroll
            for (int i = 0; i < 4; ++i)
#pragma unroll
                for (int j = 0; j < 4; ++j)
                    acc[i][j] = __builtin_amdgcn_mfma_f32_16x16x32_bf16(a2[i], b2[j], acc[i][j], 0, 0, 0);
        }
        __syncthreads();   // protect LDS before next stage
    }

    // ---- fused epilogue: +dp, tanh, *v, reduce over block's 128 cols ----
    float part[4][4];
#pragma unroll
    for (int i = 0; i < 4; ++i)
#pragma unroll
        for (int r = 0; r < 4; ++r) part[i][r] = 0.f;

#pragma unroll
    for (int j = 0; j < 4; ++j) {
        const int o = n0 + wx * 64 + j * 16 + l15;
        const float dpv = dp[b * H_ + o];
        const float vv  = v[o];
#pragma unroll
        for (int i = 0; i < 4; ++i)
#pragma unroll
            for (int r = 0; r < 4; ++r) {
                float x = acc[i][j][r] + dpv;          // D[row=quad*4+r][col=l15]
                x = fminf(10.f, fmaxf(-10.f, x));
                float e = __expf(x + x);               // e^(2x)
                float t = 1.f - 2.f * __builtin_amdgcn_rcpf(e + 1.f);
                part[i][r] += t * vv;
            }
    }
#pragma unroll
    for (int i = 0; i < 4; ++i)
#pragma unroll
        for (int r = 0; r < 4; ++r) {
            float s = part[i][r];
            s += __shfl_xor(s, 1, 64);
            s += __shfl_xor(s, 2, 64);
            s += __shfl_xor(s, 4, 64);
            s += __shfl_xor(s, 8, 64);
            if (l15 == 0)   // 4 lanes (quad) hold rows quad*4+r of frag i
                atomicAdd(&score[m0 + wy * 64 + i * 16 + quad * 4 + r], s);
        }
}

// ---------------- softmax over S in-place + zero context ----------------
__global__ __launch_bounds__(256) void softmax_kernel(float* __restrict__ out) {
    const int b = blockIdx.x;
    const int tid = threadIdx.x;
    float* sc = out + B_ * H_ + b * S_;

    ((float4*)(out + b * H_))[tid] = make_float4(0.f, 0.f, 0.f, 0.f);

    float xs[8];
    float m = -1e30f;
#pragma unroll
    for (int i = 0; i < 8; ++i) { xs[i] = sc[tid + i * 256]; m = fmaxf(m, xs[i]); }
#pragma unroll
    for (int off = 32; off > 0; off >>= 1) m = fmaxf(m, __shfl_xor(m, off, 64));
    __shared__ float redm[4];
    const int wv = tid >> 6;
    if ((tid & 63) == 0) redm[wv] = m;
    __syncthreads();
    m = fmaxf(fmaxf(redm[0], redm[1]), fmaxf(redm[2], redm[3]));

    float s = 0.f;
#pragma unroll
    for (int i = 0; i < 8; ++i) { xs[i] = __expf(xs[i] - m); s += xs[i]; }
#pragma unroll
    for (int off = 32; off > 0; off >>= 1) s += __shfl_xor(s, off, 64);
    __shared__ float reds[4];
    if ((tid & 63) == 0) reds[wv] = s;
    __syncthreads();
    s = reds[0] + reds[1] + reds[2] + reds[3];

    const float inv = 1.f / s;
#pragma unroll
    for (int i = 0; i < 8; ++i) sc[tid + i * 256] = xs[i] * inv;
}

// ---------------- context[b,h] = sum_s weights[b,s] * enc[b,s,h] ----------------
__global__ __launch_bounds__(256) void context_kernel(
        const float* __restrict__ enc, const float* __restrict__ wts,
        float* __restrict__ ctx) {
    const int b    = blockIdx.x;
    const int scnk = blockIdx.y;
    const int t    = threadIdx.x;
    const float* w  = wts + b * S_ + scnk * 256;
    const float4* e = (const float4*)(enc + ((long)b * S_ + scnk * 256) * H_);
    float4 acc = make_float4(0.f, 0.f, 0.f, 0.f);
#pragma unroll 4
    for (int s = 0; s < 256; ++s) {
        const float ww = w[s];
        const float4 ev = e[s * (H_ / 4) + t];
        acc.x = fmaf(ww, ev.x, acc.x);
        acc.y = fmaf(ww, ev.y, acc.y);
        acc.z = fmaf(ww, ev.z, acc.z);
        acc.w = fmaf(ww, ev.w, acc.w);
    }
    float* c = ctx + b * H_ + t * 4;
    atomicAdd(c + 0, acc.x);
    atomicAdd(c + 1, acc.y);
    atomicAdd(c + 2, acc.z);
    atomicAdd(c + 3, acc.w);
}

extern "C" void kernel_launch(void* const* d_in, const int* in_sizes, int n_in,
                              void* d_out, int out_size, void* d_ws, size_t ws_size,
                              hipStream_t stream) {
    const float* dec = (const float*)d_in[0];   // [64,1,1024]
    const float* enc = (const float*)d_in[1];   // [64,2048,1024]
    const float* Wh  = (const float*)d_in[2];   // [1024,1024]
    const float* Ws  = (const float*)d_in[3];   // [1024,1024]
    const float* v   = (const float*)d_in[4];   // [1024]

    float* out = (float*)d_out;
    float* ctx = out;                 // [64*1024] context
    float* wts = out + B_ * H_;       // [64*2048] scores -> weights (in place)

    float* dp  = (float*)d_ws;                                 // 256 KB
    short* Wbf = (short*)((char*)d_ws + (size_t)B_ * H_ * 4);  // 2 MB bf16
    (void)in_sizes; (void)n_in; (void)out_size; (void)ws_size;

    zero_score_kernel<<<(B_ * S_ / 4) / 256, 256, 0, stream>>>(wts);
    dec_proj_kernel<<<dim3(H_ / 256, B_), 256, 0, stream>>>(dec, Ws, dp);
    cvt_wh_kernel<<<(H_ * H_ / 4) / 256, 256, 0, stream>>>(Wh, Wbf);
    score128_kernel<<<(B_ * S_ / 128) * (H_ / 128), 256, 0, stream>>>(
        enc, Wbf, dp, v, wts);
    softmax_kernel<<<B_, 256, 0, stream>>>(out);
    context_kernel<<<dim3(B_, S_ / 256), 256, 0, stream>>>(enc, wts, ctx);
}

// Round 10
// 1088.431 us; speedup vs baseline: 1.1395x; 1.1395x over previous
//
#include <hip/hip_runtime.h>
#include <hip/hip_bf16.h>

// Bahdanau additive attention, B=64, S=2048, H=1024 (fp32 in/out).
//   score[b,s] = sum_o v[o] * tanh( (enc[b,s,:].W_h[o,:]) + dp[b,o] )
//   weights = softmax_s(score);  context[b,:] = sum_s weights[b,s]*enc[b,s,:]
//
// R9: R7 + XCD co-location swizzle on the score GEMM. R7 counters: score =
// 578us, FETCH 2.13GB = 4.2x the 512MB fp32 A (8 nb-siblings round-robin to
// 8 different XCDs -> 8 L2 copies, L3 thrash); duration == traffic/3.8TB/s,
// i.e. fetch-bound. Fix (R6-proven mechanism, now in its paying regime):
// wid = (bid&7)*1024 + (bid>>3) -> each XCD owns 128 contiguous mtiles x all
// 8 nb, siblings consecutive in issue order -> A-panel (512KB) L2-resident.
// Fused in-register fp32->bf16 A conversion kept (no cvt_enc pass).
//
// d_ws: [0,256KB) dec_proj fp32 [64][1024]; [256KB,2.25MB) W_h bf16.

#define B_ 64
#define S_ 2048
#define H_ 1024

typedef __attribute__((ext_vector_type(8))) short short8;   // 8 bf16
typedef __attribute__((ext_vector_type(4))) float floatx4;  // MFMA acc

__device__ __forceinline__ short f2bf(float f) {
    unsigned u = __float_as_uint(f);
    return (short)((u + 0x7FFFu + ((u >> 16) & 1u)) >> 16);  // RTNE
}
__device__ __forceinline__ unsigned cvtpk(float a, float b) {  // low=bf16(a), high=bf16(b), RTNE
    unsigned r;
    asm("v_cvt_pk_bf16_f32 %0, %1, %2" : "=v"(r) : "v"(a), "v"(b));
    return r;
}
__device__ __forceinline__ void gload_lds16(const void* g, void* l) {
    __builtin_amdgcn_global_load_lds(
        (const __attribute__((address_space(1))) unsigned*)g,
        (__attribute__((address_space(3))) unsigned*)l, 16, 0, 0);
}

// ---------------- zero the score region (atomicAdd target) ----------------
__global__ __launch_bounds__(256) void zero_score_kernel(float* __restrict__ sc) {
    ((float4*)sc)[blockIdx.x * 256 + threadIdx.x] = make_float4(0.f, 0.f, 0.f, 0.f);
}

// ---------------- dec_proj[b,o] = sum_h dec[b,h] * W_s[o,h] ----------------
__global__ __launch_bounds__(256) void dec_proj_kernel(
        const float* __restrict__ dec, const float* __restrict__ Ws,
        float* __restrict__ dp) {
    __shared__ float sdec[H_];
    const int b = blockIdx.y;
    const int o = blockIdx.x * 256 + threadIdx.x;
    ((float4*)sdec)[threadIdx.x] = ((const float4*)(dec + b * H_))[threadIdx.x];
    __syncthreads();
    const float4* wr = (const float4*)(Ws + (size_t)o * H_);
    float acc = 0.f;
#pragma unroll 4
    for (int i = 0; i < H_ / 4; ++i) {
        float4 wv = wr[i];
        acc += sdec[4*i+0]*wv.x + sdec[4*i+1]*wv.y + sdec[4*i+2]*wv.z + sdec[4*i+3]*wv.w;
    }
    dp[b * H_ + o] = acc;
}

// ---------------- W_h fp32 -> bf16 ----------------
__global__ __launch_bounds__(256) void cvt_wh_kernel(
        const float* __restrict__ Wh, short* __restrict__ Wbf) {
    const int i = blockIdx.x * 256 + threadIdx.x;
    float4 f = ((const float4*)Wh)[i];
    *(short4*)&Wbf[i * 4] = make_short4(f2bf(f.x), f2bf(f.y), f2bf(f.z), f2bf(f.w));
}

// ================= fused score GEMM: 128x128, fp32-A direct =================
// grid.x = 8192; XCD co-location (bijective): wid = (bid&7)*1024 + (bid>>3),
// mtile = wid>>3, nb = wid&7. XCD x owns mtiles [x*128,(x+1)*128) x all 8 nb;
// the 8 nb-siblings of a mtile are consecutive in issue order -> A-panel
// (128x1024 fp32 = 512KB) is fetched once per XCD and L2-hit by siblings.
// A: fp32 [128][64] in LDS (32KB), 16-chunk XOR swizzle: LDS[row][c] holds
//    global 16B-chunk c^(row&15); conversion to bf16 happens at read time.
// B: bf16 [128][64] in LDS (16KB), 8-chunk XOR swizzle (R3-proven).
__global__ __launch_bounds__(256, 3) void score128_kernel(
        const float* __restrict__ enc, const short* __restrict__ Wbf,
        const float* __restrict__ dp, const float* __restrict__ v,
        float* __restrict__ score) {
    __shared__ float Asf[128 * 64];   // 32 KB
    __shared__ short Bs[128 * 64];    // 16 KB

    const int tid  = threadIdx.x;
    const int wave = tid >> 6;
    const int lane = tid & 63;
    const int l15  = lane & 15;
    const int quad = lane >> 4;
    const int wy   = wave & 1;        // m-half
    const int wx   = wave >> 1;       // n-half

    // XCD co-location swizzle (bijective, 8192 = 8*1024)
    const int wid   = ((blockIdx.x & 7) << 10) | (blockIdx.x >> 3);
    const int mtile = wid >> 3;
    const int nb    = wid & 7;
    const int m0    = mtile * 128;    // global row (b*S + s)
    const int n0    = nb * 128;
    const int b     = m0 >> 11;       // 16 M-tiles per batch

    floatx4 acc[4][4];
#pragma unroll
    for (int i = 0; i < 4; ++i)
#pragma unroll
        for (int j = 0; j < 4; ++j) acc[i][j] = (floatx4){0.f, 0.f, 0.f, 0.f};

    const int swz = l15 & 7;

    // staging bases (round-invariant swizzled global addresses)
    // B: thread t, round r -> row n = r*32 + (t>>3), chunk (t&7)^(n&7); n&7=(t>>3)&7
    const int bn  = tid >> 3;
    const short* gB0 = Wbf + (size_t)(n0 + bn) * H_ + ((tid & 7) ^ (bn & 7)) * 8;
    // A: thread t, round r -> row = r*16 + (t>>4), chunk (t&15)^(row&15); row&15=t>>4
    const int an  = tid >> 4;
    const float* gA0 = enc + (size_t)(m0 + an) * H_ + (((tid & 15) ^ an) << 2);

    // read bases
    const float4* aRow = (const float4*)Asf + (wy * 64 + l15) * 16;  // +i*256 +chunk
    const short*  bLds = Bs + (wx * 64 + l15) * 64;                  // +j*1024 +chunk*8

    for (int k0 = 0; k0 < H_; k0 += 64) {
        // ---- B tile: 4 rounds async 16B ----
#pragma unroll
        for (int r = 0; r < 4; ++r)
            gload_lds16(gB0 + (size_t)r * 32 * H_ + k0,
                        (void*)(Bs + (r * 256 + wave * 64) * 8));
        // ---- A tile fp32: 8 rounds async 16B ----
#pragma unroll
        for (int r = 0; r < 8; ++r)
            gload_lds16(gA0 + (size_t)r * 16 * H_ + k0,
                        (void*)(Asf + (r * 256 + wave * 64) * 4));
        __syncthreads();   // drains vmcnt

        // ---- compute: 2 kt x (4 a-frag cvt + 4 b-frag reads, 16 MFMA) ----
#pragma unroll
        for (int kt = 0; kt < 2; ++kt) {
            const int c0 = 8 * kt + 2 * quad;   // global 16B chunk (4 floats)
            short8 a2[4], b2[4];
#pragma unroll
            for (int i = 0; i < 4; ++i) {
                float4 f0 = aRow[i * 256 + (c0 ^ l15)];
                float4 f1 = aRow[i * 256 + ((c0 + 1) ^ l15)];
                union { short8 s; unsigned u[4]; } cv;
                cv.u[0] = cvtpk(f0.x, f0.y);
                cv.u[1] = cvtpk(f0.z, f0.w);
                cv.u[2] = cvtpk(f1.x, f1.y);
                cv.u[3] = cvtpk(f1.z, f1.w);
                a2[i] = cv.s;
            }
#pragma unroll
            for (int j = 0; j < 4; ++j)
                b2[j] = *(const short8*)(bLds + j * 1024 + (((kt * 4 + quad) ^ swz) * 8));
#pragma unroll
            for (int i = 0; i < 4; ++i)
#pragma unroll
                for (int j = 0; j < 4; ++j)
                    acc[i][j] = __builtin_amdgcn_mfma_f32_16x16x32_bf16(a2[i], b2[j], acc[i][j], 0, 0, 0);
        }
        __syncthreads();   // protect LDS before next stage
    }

    // ---- fused epilogue: +dp, tanh, *v, reduce over block's 128 cols ----
    float part[4][4];
#pragma unroll
    for (int i = 0; i < 4; ++i)
#pragma unroll
        for (int r = 0; r < 4; ++r) part[i][r] = 0.f;

#pragma unroll
    for (int j = 0; j < 4; ++j) {
        const int o = n0 + wx * 64 + j * 16 + l15;
        const float dpv = dp[b * H_ + o];
        const float vv  = v[o];
#pragma unroll
        for (int i = 0; i < 4; ++i)
#pragma unroll
            for (int r = 0; r < 4; ++r) {
                float x = acc[i][j][r] + dpv;          // D[row=quad*4+r][col=l15]
                x = fminf(10.f, fmaxf(-10.f, x));
                float e = __expf(x + x);               // e^(2x)
                float t = 1.f - 2.f * __builtin_amdgcn_rcpf(e + 1.f);
                part[i][r] += t * vv;
            }
    }
#pragma unroll
    for (int i = 0; i < 4; ++i)
#pragma unroll
        for (int r = 0; r < 4; ++r) {
            float s = part[i][r];
            s += __shfl_xor(s, 1, 64);
            s += __shfl_xor(s, 2, 64);
            s += __shfl_xor(s, 4, 64);
            s += __shfl_xor(s, 8, 64);
            if (l15 == 0)   // 4 lanes (quad) hold rows quad*4+r of frag i
                atomicAdd(&score[m0 + wy * 64 + i * 16 + quad * 4 + r], s);
        }
}

// ---------------- softmax over S in-place + zero context ----------------
__global__ __launch_bounds__(256) void softmax_kernel(float* __restrict__ out) {
    const int b = blockIdx.x;
    const int tid = threadIdx.x;
    float* sc = out + B_ * H_ + b * S_;

    ((float4*)(out + b * H_))[tid] = make_float4(0.f, 0.f, 0.f, 0.f);

    float xs[8];
    float m = -1e30f;
#pragma unroll
    for (int i = 0; i < 8; ++i) { xs[i] = sc[tid + i * 256]; m = fmaxf(m, xs[i]); }
#pragma unroll
    for (int off = 32; off > 0; off >>= 1) m = fmaxf(m, __shfl_xor(m, off, 64));
    __shared__ float redm[4];
    const int wv = tid >> 6;
    if ((tid & 63) == 0) redm[wv] = m;
    __syncthreads();
    m = fmaxf(fmaxf(redm[0], redm[1]), fmaxf(redm[2], redm[3]));

    float s = 0.f;
#pragma unroll
    for (int i = 0; i < 8; ++i) { xs[i] = __expf(xs[i] - m); s += xs[i]; }
#pragma unroll
    for (int off = 32; off > 0; off >>= 1) s += __shfl_xor(s, off, 64);
    __shared__ float reds[4];
    if ((tid & 63) == 0) reds[wv] = s;
    __syncthreads();
    s = reds[0] + reds[1] + reds[2] + reds[3];

    const float inv = 1.f / s;
#pragma unroll
    for (int i = 0; i < 8; ++i) sc[tid + i * 256] = xs[i] * inv;
}

// ---------------- context[b,h] = sum_s weights[b,s] * enc[b,s,h] ----------------
__global__ __launch_bounds__(256) void context_kernel(
        const float* __restrict__ enc, const float* __restrict__ wts,
        float* __restrict__ ctx) {
    const int b    = blockIdx.x;
    const int scnk = blockIdx.y;
    const int t    = threadIdx.x;
    const float* w  = wts + b * S_ + scnk * 256;
    const float4* e = (const float4*)(enc + ((long)b * S_ + scnk * 256) * H_);
    float4 acc = make_float4(0.f, 0.f, 0.f, 0.f);
#pragma unroll 4
    for (int s = 0; s < 256; ++s) {
        const float ww = w[s];
        const float4 ev = e[s * (H_ / 4) + t];
        acc.x = fmaf(ww, ev.x, acc.x);
        acc.y = fmaf(ww, ev.y, acc.y);
        acc.z = fmaf(ww, ev.z, acc.z);
        acc.w = fmaf(ww, ev.w, acc.w);
    }
    float* c = ctx + b * H_ + t * 4;
    atomicAdd(c + 0, acc.x);
    atomicAdd(c + 1, acc.y);
    atomicAdd(c + 2, acc.z);
    atomicAdd(c + 3, acc.w);
}

extern "C" void kernel_launch(void* const* d_in, const int* in_sizes, int n_in,
                              void* d_out, int out_size, void* d_ws, size_t ws_size,
                              hipStream_t stream) {
    const float* dec = (const float*)d_in[0];   // [64,1,1024]
    const float* enc = (const float*)d_in[1];   // [64,2048,1024]
    const float* Wh  = (const float*)d_in[2];   // [1024,1024]
    const float* Ws  = (const float*)d_in[3];   // [1024,1024]
    const float* v   = (const float*)d_in[4];   // [1024]

    float* out = (float*)d_out;
    float* ctx = out;                 // [64*1024] context
    float* wts = out + B_ * H_;       // [64*2048] scores -> weights (in place)

    float* dp  = (float*)d_ws;                                 // 256 KB
    short* Wbf = (short*)((char*)d_ws + (size_t)B_ * H_ * 4);  // 2 MB bf16
    (void)in_sizes; (void)n_in; (void)out_size; (void)ws_size;

    zero_score_kernel<<<(B_ * S_ / 4) / 256, 256, 0, stream>>>(wts);
    dec_proj_kernel<<<dim3(H_ / 256, B_), 256, 0, stream>>>(dec, Ws, dp);
    cvt_wh_kernel<<<(H_ * H_ / 4) / 256, 256, 0, stream>>>(Wh, Wbf);
    score128_kernel<<<(B_ * S_ / 128) * (H_ / 128), 256, 0, stream>>>(
        enc, Wbf, dp, v, wts);
    softmax_kernel<<<B_, 256, 0, stream>>>(out);
    context_kernel<<<dim3(B_, S_ / 256), 256, 0, stream>>>(enc, wts, ctx);
}